// Round 2
// baseline (12793.640 us; speedup 1.0000x reference)
//
#include <hip/hip_runtime.h>

// ============================================================================
// AFAR: channel-attention -> per-channel truncated-SVD recon -> spatial attn.
// A_k = P*A, P = step(G - t), G = A*A^T. t from mixed-precision Householder
// tridiag (fp32 LDS storage, fp64 arithmetic) + fp64 Sturm bisection.
// Projector via "polar express" sign schedule (equioscillation cubics).
// ============================================================================

#define NCH 256
#define N 256
#define NN 65536
#define NS_MAX 40
#define TRI(i, j) ((((i) * ((i) + 1)) >> 1) + (j))

// small-region offsets (float units; double regions at even offsets)
#define OFF_K 0        // int[256]
#define OFF_MODE 256   // int[256]: 0 -> A_k=0, 1 -> A_k=A, 2 -> project
#define OFF_MC 512     // int[256]
#define OFF_COEF 768   // float[256][2*NS_MAX]
#define OFF_SUM 21248  // float[65536]
#define OFF_MAXHW 86784 // float[65536]
#define OFF_MEAND 152320 // double[256]
#define OFF_MAXD 152832  // double[256]
#define OFF_T 153344     // double[256]
#define OFF_ALPHA 153856 // double[256]
#define OFF_AQ 154368    // double[256][256] tridiag diag
#define OFF_BQ 285440    // double[256][256] tridiag offdiag
#define SMALL_FLOATS 416512

static const float EPSF = 2.220446049250313e-16f;

__device__ __forceinline__ double block_sum256d(double v, double* red, int tid) {
  for (int off = 32; off; off >>= 1) v += __shfl_down(v, off, 64);
  __syncthreads(); // protect red from previous use
  if ((tid & 63) == 0) red[tid >> 6] = v;
  __syncthreads();
  return red[0] + red[1] + red[2] + red[3];
}

// ---------------------------------------------------------------------------
// 1) per-channel mean & max over H*W (fp64 sum)
// ---------------------------------------------------------------------------
__global__ __launch_bounds__(256) void k_chan_stats(const float* __restrict__ x,
                                                    float* __restrict__ small) {
  int c = blockIdx.x, tid = threadIdx.x;
  const float4* xc = (const float4*)(x + (size_t)c * NN);
  double s = 0.0;
  float m = -1e30f;
  for (int i = tid; i < NN / 4; i += 256) {
    float4 v = xc[i];
    s += (double)v.x + (double)v.y + (double)v.z + (double)v.w;
    m = fmaxf(m, fmaxf(fmaxf(v.x, v.y), fmaxf(v.z, v.w)));
  }
  __shared__ double rs[4];
  __shared__ float rm[4];
  for (int off = 32; off; off >>= 1) {
    s += __shfl_down(s, off, 64);
    m = fmaxf(m, __shfl_down(m, off, 64));
  }
  if ((tid & 63) == 0) { rs[tid >> 6] = s; rm[tid >> 6] = m; }
  __syncthreads();
  if (tid == 0) {
    ((double*)(small + OFF_MEAND))[c] = (rs[0] + rs[1] + rs[2] + rs[3]) / (double)NN;
    ((double*)(small + OFF_MAXD))[c] =
        (double)fmaxf(fmaxf(rm[0], rm[1]), fmaxf(rm[2], rm[3]));
  }
}

// ---------------------------------------------------------------------------
// 2) shared-MLP channel attention (fp64) -> gates yc -> k_c, mode_c
// ---------------------------------------------------------------------------
__global__ __launch_bounds__(256) void k_attention(const float* __restrict__ w1,
                                                   const float* __restrict__ w2,
                                                   const int* __restrict__ kvp,
                                                   float* __restrict__ small) {
  int tid = threadIdx.x;
  __shared__ double ha[16], hm[16], redd[8], ymn[256], ymx[256];
  double va = ((const double*)(small + OFF_MEAND))[tid];
  double vm = ((const double*)(small + OFF_MAXD))[tid];
  for (int r = 0; r < 16; ++r) {
    double wv = (double)w1[r * 256 + tid];
    double pa = wv * va, pm = wv * vm;
    for (int off = 32; off; off >>= 1) {
      pa += __shfl_down(pa, off, 64);
      pm += __shfl_down(pm, off, 64);
    }
    if ((tid & 63) == 0) { redd[tid >> 6] = pa; redd[4 + (tid >> 6)] = pm; }
    __syncthreads();
    if (tid == 0) {
      ha[r] = fmax(redd[0] + redd[1] + redd[2] + redd[3], 0.0);
      hm[r] = fmax(redd[4] + redd[5] + redd[6] + redd[7], 0.0);
    }
    __syncthreads();
  }
  double ya = 0.0, ym = 0.0;
  for (int r = 0; r < 16; ++r) {
    double wv = (double)w2[tid * 16 + r];
    ya += ha[r] * wv;
    ym += hm[r] * wv;
  }
  double y = 1.0 / (1.0 + exp(-(ya + ym)));
  ymn[tid] = y; ymx[tid] = y;
  __syncthreads();
  for (int off = 128; off; off >>= 1) {
    if (tid < off) {
      ymn[tid] = fmin(ymn[tid], ymn[tid + off]);
      ymx[tid] = fmax(ymx[tid], ymx[tid + off]);
    }
    __syncthreads();
  }
  double yc = (y - ymn[0]) / (ymx[0] - ymn[0] + 1e-20);
  int kv = kvp[0];
  int k = (int)floor(256.0 * (double)kv * yc);
  int mode = (k <= 0) ? 0 : ((k >= 256) ? 1 : 2);
  int* ip = (int*)small;
  ip[OFF_K + tid] = k;
  ip[OFF_MODE + tid] = mode;
}

// ---------------------------------------------------------------------------
// GEMM core: 64x64 tile, 256 threads, 4x4 micro-tile, K=256
// ---------------------------------------------------------------------------
#define GEMM_LOAD_AT(Aptr)                                                     \
  {                                                                            \
    int row = tid >> 2, q = tid & 3;                                           \
    const float4 a4 =                                                          \
        *(const float4*)((Aptr) + (size_t)(i0 + row) * N + kt * 16 + q * 4);   \
    As[row][q * 4 + 0] = a4.x; As[row][q * 4 + 1] = a4.y;                      \
    As[row][q * 4 + 2] = a4.z; As[row][q * 4 + 3] = a4.w;                      \
  }
#define GEMM_LOAD_BT(Bptr)                                                     \
  {                                                                            \
    int row = tid >> 2, q = tid & 3;                                           \
    const float4 b4 =                                                          \
        *(const float4*)((Bptr) + (size_t)(j0 + row) * N + kt * 16 + q * 4);   \
    Bs[row][q * 4 + 0] = b4.x; Bs[row][q * 4 + 1] = b4.y;                      \
    Bs[row][q * 4 + 2] = b4.z; Bs[row][q * 4 + 3] = b4.w;                      \
  }
#define GEMM_LOAD_BN(Bptr)                                                     \
  {                                                                            \
    int kk2 = tid >> 4, j4 = (tid & 15) * 4;                                   \
    const float4 b4 =                                                          \
        *(const float4*)((Bptr) + (size_t)(kt * 16 + kk2) * N + j0 + j4);      \
    Bs[j4 + 0][kk2] = b4.x; Bs[j4 + 1][kk2] = b4.y;                            \
    Bs[j4 + 2][kk2] = b4.z; Bs[j4 + 3][kk2] = b4.w;                            \
  }
#define GEMM_INNER                                                             \
  for (int kk = 0; kk < 16; ++kk) {                                            \
    float ra0 = As[ty4 + 0][kk], ra1 = As[ty4 + 1][kk];                        \
    float ra2 = As[ty4 + 2][kk], ra3 = As[ty4 + 3][kk];                        \
    float rb0 = Bs[tx4 + 0][kk], rb1 = Bs[tx4 + 1][kk];                        \
    float rb2 = Bs[tx4 + 2][kk], rb3 = Bs[tx4 + 3][kk];                        \
    acc[0][0] += ra0 * rb0; acc[0][1] += ra0 * rb1;                            \
    acc[0][2] += ra0 * rb2; acc[0][3] += ra0 * rb3;                            \
    acc[1][0] += ra1 * rb0; acc[1][1] += ra1 * rb1;                            \
    acc[1][2] += ra1 * rb2; acc[1][3] += ra1 * rb3;                            \
    acc[2][0] += ra2 * rb0; acc[2][1] += ra2 * rb1;                            \
    acc[2][2] += ra2 * rb2; acc[2][3] += ra2 * rb3;                            \
    acc[3][0] += ra3 * rb0; acc[3][1] += ra3 * rb1;                            \
    acc[3][2] += ra3 * rb2; acc[3][3] += ra3 * rb3;                            \
  }

// 3) G = A*A^T per channel
__global__ __launch_bounds__(256) void k_gram(const float* __restrict__ x,
                                              float* __restrict__ bufA, int base) {
  __shared__ float As[64][17], Bs[64][17];
  int tid = threadIdx.x, tx4 = (tid & 15) * 4, ty4 = (tid >> 4) * 4;
  int i0 = blockIdx.x * 64, j0 = blockIdx.y * 64;
  const float* A = x + (size_t)(base + blockIdx.z) * NN;
  float acc[4][4] = {};
  for (int kt = 0; kt < 16; ++kt) {
    GEMM_LOAD_AT(A); GEMM_LOAD_BT(A);
    __syncthreads();
    GEMM_INNER;
    __syncthreads();
  }
  float* Cc = bufA + (size_t)blockIdx.z * NN;
  for (int i = 0; i < 4; ++i)
    *(float4*)(Cc + (size_t)(i0 + ty4 + i) * N + j0 + tx4) =
        make_float4(acc[i][0], acc[i][1], acc[i][2], acc[i][3]);
}

// ---------------------------------------------------------------------------
// 4) Householder tridiag: packed fp32 P in LDS, fp64 arithmetic throughout
// ---------------------------------------------------------------------------
__global__ __launch_bounds__(256) void k_tridiag(const float* __restrict__ Gall,
                                                 float* __restrict__ small, int base) {
  extern __shared__ double dls[];
  double* wd = dls;                 // 256 doubles
  double* redd = dls + 256;         // 8 doubles
  float* P = (float*)(dls + 264);   // 32896 floats packed lower
  float* u = P + 32896;             // 256 floats
  int tid = threadIdx.x;
  int c = base + blockIdx.x;
  const int* ip = (const int*)small;
  if (ip[OFF_MODE + c] != 2) return;
  const float* G = Gall + (size_t)blockIdx.x * NN;
  double* aq = (double*)(small + OFF_AQ) + (size_t)c * 256;
  double* bq = (double*)(small + OFF_BQ) + (size_t)c * 256;

  for (int i = 0; i < N; ++i)
    if (tid <= i) P[TRI(i, tid)] = G[i * N + tid];
  __syncthreads();

  for (int j = 0; j + 2 < N; ++j) {
    if (tid >= j + 1) u[tid] = P[TRI(tid, j)];
    __syncthreads();
    double ud = (double)u[tid];
    double part = (tid >= j + 2) ? ud * ud : 0.0;
    double sigma = block_sum256d(part, redd, tid);
    double x0 = (double)u[j + 1];
    if (sigma <= 1e-40) { // column already tridiagonal
      if (tid == 0) bq[j] = x0;
      __syncthreads();
      continue;
    }
    double nu = sqrt(x0 * x0 + sigma);
    double bsub = (x0 >= 0.0) ? -nu : nu;
    double beta = 1.0 / (nu * (nu + fabs(x0)));
    __syncthreads(); // everyone has read u[j+1] before overwrite
    if (tid == j + 1) u[tid] = (float)(x0 - bsub);
    __syncthreads();
    double pi = 0.0;
    if (tid >= j + 1) {
      for (int l = j + 1; l <= tid; ++l)
        pi += (double)P[TRI(tid, l)] * (double)u[l];
      for (int l = tid + 1; l < N; ++l)
        pi += (double)P[TRI(l, tid)] * (double)u[l];
      pi *= beta;
    }
    double kpart = (tid >= j + 1) ? (double)u[tid] * pi : 0.0;
    double K = block_sum256d(kpart, redd, tid) * beta * 0.5;
    wd[tid] = pi - K * (double)u[tid];
    __syncthreads();
    if (tid >= j + 1) {
      double ui = (double)u[tid], wi = wd[tid];
      for (int l = j + 1; l <= tid; ++l)
        P[TRI(tid, l)] =
            (float)((double)P[TRI(tid, l)] - ui * wd[l] - wi * (double)u[l]);
    }
    if (tid == 0) bq[j] = bsub;
    __syncthreads();
  }
  aq[tid] = (double)P[TRI(tid, tid)];
  if (tid == 0) bq[N - 2] = (double)P[TRI(N - 1, N - 2)];
}

// ---------------------------------------------------------------------------
// 5) fp64 Sturm bisection -> t, alpha, polar-express coefficient schedule
// ---------------------------------------------------------------------------
__device__ __forceinline__ int sturm_count_d(const double* a, const double* b,
                                             double t) {
  double d = a[0] - t;
  int cnt = (d < 0.0);
  for (int i = 1; i < N; ++i) {
    double den = d;
    if (fabs(den) < 1e-20) den = (den < 0.0) ? -1e-20 : 1e-20;
    double bb = b[i - 1];
    d = (a[i] - t) - bb * bb / den;
    cnt += (d < 0.0);
  }
  return cnt; // #{eig < t}
}

__global__ void k_bisect(float* __restrict__ small, int base, int cc) {
  int idx = blockIdx.x * 64 + threadIdx.x;
  if (idx >= cc) return;
  int c = base + idx;
  int* ip = (int*)small;
  if (ip[OFF_MODE + c] != 2) { ip[OFF_MC + c] = 0; return; }
  int k = ip[OFF_K + c];
  const double* a = (const double*)(small + OFF_AQ) + (size_t)c * 256;
  const double* b = (const double*)(small + OFF_BQ) + (size_t)c * 256;
  double lo = 1e300, hi = -1e300;
  for (int i = 0; i < N; ++i) {
    double r = (i > 0 ? fabs(b[i - 1]) : 0.0) + (i < N - 1 ? fabs(b[i]) : 0.0);
    lo = fmin(lo, a[i] - r);
    hi = fmax(hi, a[i] + r);
  }
  double lamk = 0.0, lamk1 = 0.0;
  for (int which = 0; which < 2; ++which) {
    int j = (which == 0) ? (N - k + 1) : (N - k); // ascending index of mu_j
    double l0 = lo, h0 = hi;
    for (int it = 0; it < 60; ++it) {
      double mid = 0.5 * (l0 + h0);
      if (sturm_count_d(a, b, mid) >= j) h0 = mid; else l0 = mid;
    }
    double v = 0.5 * (l0 + h0);
    if (which == 0) lamk = v; else lamk1 = v;
  }
  double t = 0.5 * (lamk + lamk1);
  double gap = fmax(lamk - lamk1, 0.0);
  double alpha = 1.002 * fmax(hi - t, t - lo) + 1e-30;
  double g0 = fmax(gap / (2.0 * alpha), 2e-6);
  // polar-express schedule: equioscillation cubic per iteration
  float* cf = small + OFF_COEF + (size_t)c * (2 * NS_MAX);
  double l = fmin(g0, 0.99);
  int m = 0;
  while (m < NS_MAX - 2 && l < 0.9999) {
    double aa = sqrt(27.0 / (4.0 * (1.0 + l + l * l)));
    double bb = (4.0 / 27.0) * aa * aa * aa;
    cf[2 * m] = (float)aa;
    cf[2 * m + 1] = (float)bb;
    double pl = aa * l - bb * l * l * l;
    double p1 = aa - bb;
    l = fmin(pl, p1);
    m++;
  }
  for (int e = 0; e < 2; ++e) { cf[2 * m] = 1.5f; cf[2 * m + 1] = 0.5f; m++; }
  ip[OFF_MC + c] = m;
  ((double*)(small + OFF_T))[c] = t;
  ((double*)(small + OFF_ALPHA))[c] = alpha;
}

// 6) X0 = (G - t*I)/alpha (in place on bufA, fp64 scale)
__global__ void k_x0(const float* __restrict__ small, float* __restrict__ bufA,
                     int base) {
  int ci = blockIdx.y, c = base + ci;
  const int* ip = (const int*)small;
  if (ip[OFF_MODE + c] != 2) return;
  double t = ((const double*)(small + OFF_T))[c];
  double inva = 1.0 / ((const double*)(small + OFF_ALPHA))[c];
  float* X = bufA + (size_t)ci * NN;
  int r = blockIdx.x, tid = threadIdx.x;
  double g = (double)X[r * N + tid];
  if (tid == r) g -= t;
  X[r * N + tid] = (float)(g * inva);
}

// 7a) S = X*X  (X symmetric -> X*X^T)
__global__ __launch_bounds__(256) void k_ns1(const float* __restrict__ src,
                                             float* __restrict__ Sb,
                                             const float* __restrict__ small,
                                             int base, int it) {
  const int* ip = (const int*)small;
  int c = base + blockIdx.z;
  if (ip[OFF_MODE + c] != 2 || it >= ip[OFF_MC + c]) return;
  __shared__ float As[64][17], Bs[64][17];
  int tid = threadIdx.x, tx4 = (tid & 15) * 4, ty4 = (tid >> 4) * 4;
  int i0 = blockIdx.x * 64, j0 = blockIdx.y * 64;
  const float* X = src + (size_t)blockIdx.z * NN;
  float acc[4][4] = {};
  for (int kt = 0; kt < 16; ++kt) {
    GEMM_LOAD_AT(X); GEMM_LOAD_BT(X);
    __syncthreads();
    GEMM_INNER;
    __syncthreads();
  }
  float* Cc = Sb + (size_t)blockIdx.z * NN;
  for (int i = 0; i < 4; ++i)
    *(float4*)(Cc + (size_t)(i0 + ty4 + i) * N + j0 + tx4) =
        make_float4(acc[i][0], acc[i][1], acc[i][2], acc[i][3]);
}

// 7b) Y = a*X - b*X*S   (per-channel polar-express coefficients)
__global__ __launch_bounds__(256) void k_ns2(const float* __restrict__ src,
                                             const float* __restrict__ Sb,
                                             float* __restrict__ dst,
                                             const float* __restrict__ small,
                                             int base, int it) {
  const int* ip = (const int*)small;
  int c = base + blockIdx.z;
  if (ip[OFF_MODE + c] != 2 || it >= ip[OFF_MC + c]) return;
  float ca = small[OFF_COEF + (size_t)c * (2 * NS_MAX) + 2 * it];
  float cb = small[OFF_COEF + (size_t)c * (2 * NS_MAX) + 2 * it + 1];
  __shared__ float As[64][17], Bs[64][17];
  int tid = threadIdx.x, tx4 = (tid & 15) * 4, ty4 = (tid >> 4) * 4;
  int i0 = blockIdx.x * 64, j0 = blockIdx.y * 64;
  const float* X = src + (size_t)blockIdx.z * NN;
  const float* S = Sb + (size_t)blockIdx.z * NN;
  float acc[4][4] = {};
  for (int kt = 0; kt < 16; ++kt) {
    GEMM_LOAD_AT(X); GEMM_LOAD_BT(S);
    __syncthreads();
    GEMM_INNER;
    __syncthreads();
  }
  float* Y = dst + (size_t)blockIdx.z * NN;
  for (int i = 0; i < 4; ++i) {
    const float4 xr = *(const float4*)(X + (size_t)(i0 + ty4 + i) * N + j0 + tx4);
    *(float4*)(Y + (size_t)(i0 + ty4 + i) * N + j0 + tx4) =
        make_float4(ca * xr.x - cb * acc[i][0], ca * xr.y - cb * acc[i][1],
                    ca * xr.z - cb * acc[i][2], ca * xr.w - cb * acc[i][3]);
  }
}

// 8) A_k = 0.5*(sign(X)*A + A)  (modes: 0 -> zeros, 1 -> copy A)
__global__ __launch_bounds__(256) void k_proj(const float* __restrict__ bufA,
                                              const float* __restrict__ bufB,
                                              const float* __restrict__ x,
                                              float* __restrict__ bufC,
                                              const float* __restrict__ small,
                                              int base) {
  const int* ip = (const int*)small;
  int ci = blockIdx.z, c = base + ci;
  int mode = ip[OFF_MODE + c];
  int tid = threadIdx.x, tx4 = (tid & 15) * 4, ty4 = (tid >> 4) * 4;
  int i0 = blockIdx.x * 64, j0 = blockIdx.y * 64;
  float* Cc = bufC + (size_t)ci * NN;
  const float* xc = x + (size_t)c * NN;
  if (mode == 0) {
    for (int i = 0; i < 4; ++i)
      *(float4*)(Cc + (size_t)(i0 + ty4 + i) * N + j0 + tx4) =
          make_float4(0.f, 0.f, 0.f, 0.f);
    return;
  }
  if (mode == 1) {
    for (int i = 0; i < 4; ++i)
      *(float4*)(Cc + (size_t)(i0 + ty4 + i) * N + j0 + tx4) =
          *(const float4*)(xc + (size_t)(i0 + ty4 + i) * N + j0 + tx4);
    return;
  }
  int mc = ip[OFF_MC + c];
  const float* Xh = ((mc & 1) ? bufB : bufA) + (size_t)ci * NN;
  __shared__ float As[64][17], Bs[64][17];
  float acc[4][4] = {};
  for (int kt = 0; kt < 16; ++kt) {
    GEMM_LOAD_AT(Xh); GEMM_LOAD_BN(xc);
    __syncthreads();
    GEMM_INNER;
    __syncthreads();
  }
  for (int i = 0; i < 4; ++i) {
    const float4 xr = *(const float4*)(xc + (size_t)(i0 + ty4 + i) * N + j0 + tx4);
    *(float4*)(Cc + (size_t)(i0 + ty4 + i) * N + j0 + tx4) =
        make_float4(0.5f * (acc[i][0] + xr.x), 0.5f * (acc[i][1] + xr.y),
                    0.5f * (acc[i][2] + xr.z), 0.5f * (acc[i][3] + xr.w));
  }
}

// 9) accumulate sum & max over channels
__global__ void k_accum(const float* __restrict__ bufC, float* __restrict__ sum_hw,
                        float* __restrict__ max_hw, int cc, int first) {
  int p = blockIdx.x * 256 + threadIdx.x;
  float s = first ? 0.f : sum_hw[p];
  float m = first ? -1e30f : max_hw[p];
  for (int ci = 0; ci < cc; ++ci) {
    float v = bufC[(size_t)ci * NN + p];
    s += v;
    m = fmaxf(m, v);
  }
  sum_hw[p] = s;
  max_hw[p] = m;
}

// 10) 7x7 conv (pad 3) on [avg, max] -> clamp EPS -> sigmoid
__global__ void k_conv(const float* __restrict__ sum_hw, const float* __restrict__ max_hw,
                       const float* __restrict__ cw, float* __restrict__ out) {
  int p = blockIdx.x * 256 + threadIdx.x;
  int h = p >> 8, w = p & 255;
  float acc = 0.f;
  for (int dy = 0; dy < 7; ++dy) {
    int hy = h + dy - 3;
    if (hy < 0 || hy > 255) continue;
    for (int dx = 0; dx < 7; ++dx) {
      int wx = w + dx - 3;
      if (wx < 0 || wx > 255) continue;
      int q = hy * 256 + wx;
      acc += cw[dy * 7 + dx] * (sum_hw[q] * (1.f / 256.f)) +
             cw[49 + dy * 7 + dx] * max_hw[q];
    }
  }
  acc = fmaxf(acc, EPSF);
  out[p] = 1.f / (1.f + expf(-acc));
}

// ---------------------------------------------------------------------------
extern "C" void kernel_launch(void* const* d_in, const int* in_sizes, int n_in,
                              void* d_out, int out_size, void* d_ws, size_t ws_size,
                              hipStream_t stream) {
  const float* x = (const float*)d_in[0];
  const float* w1 = (const float*)d_in[1];
  const float* w2 = (const float*)d_in[2];
  const float* cw = (const float*)d_in[3];
  const int* kv = (const int*)d_in[4];
  float* out = (float*)d_out;
  float* small = (float*)d_ws;

  size_t small_bytes = (size_t)SMALL_FLOATS * 4;
  size_t avail = ws_size > small_bytes ? ws_size - small_bytes : 0;
  long chunk = (long)(avail / (3ull * NN * 4)); // 3 fp32 matrices per channel
  if (chunk > NCH) chunk = NCH;
  if (chunk < 1) chunk = 1;
  float* bufA = small + SMALL_FLOATS;
  float* bufB = bufA + (size_t)chunk * NN;
  float* bufC = bufB + (size_t)chunk * NN;

  const int tridiag_lds = 264 * 8 + 32896 * 4 + 256 * 4; // 134720 B
  hipFuncSetAttribute((const void*)k_tridiag,
                      hipFuncAttributeMaxDynamicSharedMemorySize, tridiag_lds);

  k_chan_stats<<<NCH, 256, 0, stream>>>(x, small);
  k_attention<<<1, 256, 0, stream>>>(w1, w2, kv, small);

  for (int base = 0; base < NCH; base += (int)chunk) {
    int cc = (NCH - base < (int)chunk) ? (NCH - base) : (int)chunk;
    dim3 g44(4, 4, cc);
    k_gram<<<g44, 256, 0, stream>>>(x, bufA, base);
    k_tridiag<<<cc, 256, tridiag_lds, stream>>>(bufA, small, base);
    k_bisect<<<(cc + 63) / 64, 64, 0, stream>>>(small, base, cc);
    k_x0<<<dim3(N, cc), 256, 0, stream>>>(small, bufA, base);
    for (int it = 0; it < NS_MAX; ++it) {
      const float* src = (it & 1) ? bufB : bufA;
      float* dst = (it & 1) ? bufA : bufB;
      k_ns1<<<g44, 256, 0, stream>>>(src, bufC, small, base, it);
      k_ns2<<<g44, 256, 0, stream>>>(src, bufC, dst, small, base, it);
    }
    k_proj<<<g44, 256, 0, stream>>>(bufA, bufB, x, bufC, small, base);
    k_accum<<<256, 256, 0, stream>>>(bufC, small + OFF_SUM, small + OFF_MAXHW, cc,
                                     base == 0 ? 1 : 0);
  }
  k_conv<<<256, 256, 0, stream>>>(small + OFF_SUM, small + OFF_MAXHW, cw, out);
}

// Round 4
// 10010.122 us; speedup vs baseline: 1.2781x; 1.2781x over previous
//
#include <hip/hip_runtime.h>

// ============================================================================
// AFAR: channel-attention -> per-channel truncated-SVD recon -> spatial attn.
// A_k = P*A, P = step(G - t), G = A*A^T. t from mixed-precision Householder
// tridiag (fp32 LDS storage, fp64 arithmetic, readlane/broadcast operand
// fetch) + fp64 Sturm bisect. Projector via polar-express sign schedule;
// symmetric GEMMs compute 10/16 tiles and mirror.
// ============================================================================

#define NCH 256
#define N 256
#define NN 65536
#define NS_MAX 24
#define TRI(i, j) ((((i) * ((i) + 1)) >> 1) + (j))

// small-region float offsets inside d_ws (double regions 8B-aligned)
#define OFF_K 0          // int[256]
#define OFF_MODE 256     // int[256]: 0 -> A_k=0, 1 -> A_k=A, 2 -> project
#define OFF_MC 512       // int[256]
#define OFF_COEF 768     // float[256][2*NS_MAX]
#define OFF_SUM 13056    // float[65536]
#define OFF_MAXHW 78592  // float[65536]
#define OFF_MEAND 144128 // double[256]
#define OFF_MAXD 144640  // double[256]
#define OFF_T 145152     // double[256]
#define OFF_ALPHA 145664 // double[256]
#define OFF_AQ 146176    // double[256][256]
#define OFF_BQ 277248    // double[256][256]
#define SMALL_FLOATS 408320

static const float EPSF = 2.220446049250313e-16f;

__device__ __forceinline__ float rdlane(float v, int l) {
  return __uint_as_float(__builtin_amdgcn_readlane(__float_as_uint(v), l));
}

__device__ __forceinline__ double block_sum256d(double v, double* red, int tid) {
  for (int off = 32; off; off >>= 1) v += __shfl_down(v, off, 64);
  __syncthreads(); // protect red from previous use
  if ((tid & 63) == 0) red[tid >> 6] = v;
  __syncthreads();
  return red[0] + red[1] + red[2] + red[3];
}

// ---------------------------------------------------------------------------
// 1) per-channel mean & max over H*W (fp64 sum)
// ---------------------------------------------------------------------------
__global__ __launch_bounds__(256) void k_chan_stats(const float* __restrict__ x,
                                                    float* __restrict__ small) {
  int c = blockIdx.x, tid = threadIdx.x;
  const float4* xc = (const float4*)(x + (size_t)c * NN);
  double s = 0.0;
  float m = -1e30f;
  for (int i = tid; i < NN / 4; i += 256) {
    float4 v = xc[i];
    s += (double)v.x + (double)v.y + (double)v.z + (double)v.w;
    m = fmaxf(m, fmaxf(fmaxf(v.x, v.y), fmaxf(v.z, v.w)));
  }
  __shared__ double rs[4];
  __shared__ float rm[4];
  for (int off = 32; off; off >>= 1) {
    s += __shfl_down(s, off, 64);
    m = fmaxf(m, __shfl_down(m, off, 64));
  }
  if ((tid & 63) == 0) { rs[tid >> 6] = s; rm[tid >> 6] = m; }
  __syncthreads();
  if (tid == 0) {
    ((double*)(small + OFF_MEAND))[c] = (rs[0] + rs[1] + rs[2] + rs[3]) / (double)NN;
    ((double*)(small + OFF_MAXD))[c] =
        (double)fmaxf(fmaxf(rm[0], rm[1]), fmaxf(rm[2], rm[3]));
  }
}

// ---------------------------------------------------------------------------
// 2) shared-MLP channel attention (fp64) -> gates yc -> k_c, mode_c
// ---------------------------------------------------------------------------
__global__ __launch_bounds__(256) void k_attention(const float* __restrict__ w1,
                                                   const float* __restrict__ w2,
                                                   const int* __restrict__ kvp,
                                                   float* __restrict__ small) {
  int tid = threadIdx.x;
  __shared__ double ha[16], hm[16], redd[8], ymn[256], ymx[256];
  double va = ((const double*)(small + OFF_MEAND))[tid];
  double vm = ((const double*)(small + OFF_MAXD))[tid];
  for (int r = 0; r < 16; ++r) {
    double wv = (double)w1[r * 256 + tid];
    double pa = wv * va, pm = wv * vm;
    for (int off = 32; off; off >>= 1) {
      pa += __shfl_down(pa, off, 64);
      pm += __shfl_down(pm, off, 64);
    }
    if ((tid & 63) == 0) { redd[tid >> 6] = pa; redd[4 + (tid >> 6)] = pm; }
    __syncthreads();
    if (tid == 0) {
      ha[r] = fmax(redd[0] + redd[1] + redd[2] + redd[3], 0.0);
      hm[r] = fmax(redd[4] + redd[5] + redd[6] + redd[7], 0.0);
    }
    __syncthreads();
  }
  double ya = 0.0, ym = 0.0;
  for (int r = 0; r < 16; ++r) {
    double wv = (double)w2[tid * 16 + r];
    ya += ha[r] * wv;
    ym += hm[r] * wv;
  }
  double y = 1.0 / (1.0 + exp(-(ya + ym)));
  ymn[tid] = y; ymx[tid] = y;
  __syncthreads();
  for (int off = 128; off; off >>= 1) {
    if (tid < off) {
      ymn[tid] = fmin(ymn[tid], ymn[tid + off]);
      ymx[tid] = fmax(ymx[tid], ymx[tid + off]);
    }
    __syncthreads();
  }
  double yc = (y - ymn[0]) / (ymx[0] - ymn[0] + 1e-20);
  int kv = kvp[0];
  int k = (int)floor(256.0 * (double)kv * yc);
  int mode = (k <= 0) ? 0 : ((k >= 256) ? 1 : 2);
  int* ip = (int*)small;
  ip[OFF_K + tid] = k;
  ip[OFF_MODE + tid] = mode;
}

// ---------------------------------------------------------------------------
// GEMM core helpers: 64x64 tile, 256 threads, 4x4 micro-tile, k-major LDS
// ---------------------------------------------------------------------------
#define GEMM_VARS                                                              \
  int tid = threadIdx.x;                                                       \
  int tx4 = (tid & 15) * 4, ty4 = (tid >> 4) * 4;                              \
  int srow = tid >> 2, sq = tid & 3;                                           \
  int skk = tid >> 4, sj4 = (tid & 15) * 4;                                    \
  (void)skk; (void)sj4;

#define STORE_T(Sm, v)                                                         \
  Sm[sq * 4 + 0][srow] = v.x; Sm[sq * 4 + 1][srow] = v.y;                      \
  Sm[sq * 4 + 2][srow] = v.z; Sm[sq * 4 + 3][srow] = v.w;

#define GEMM_INNER16                                                           \
  _Pragma("unroll") for (int kk = 0; kk < 16; ++kk) {                          \
    const float4 a4 = *(const float4*)&As[kk][ty4];                            \
    const float4 b4 = *(const float4*)&Bs[kk][tx4];                            \
    acc[0][0] += a4.x * b4.x; acc[0][1] += a4.x * b4.y;                        \
    acc[0][2] += a4.x * b4.z; acc[0][3] += a4.x * b4.w;                        \
    acc[1][0] += a4.y * b4.x; acc[1][1] += a4.y * b4.y;                        \
    acc[1][2] += a4.y * b4.z; acc[1][3] += a4.y * b4.w;                        \
    acc[2][0] += a4.z * b4.x; acc[2][1] += a4.z * b4.y;                        \
    acc[2][2] += a4.z * b4.z; acc[2][3] += a4.z * b4.w;                        \
    acc[3][0] += a4.w * b4.x; acc[3][1] += a4.w * b4.y;                        \
    acc[3][2] += a4.w * b4.z; acc[3][3] += a4.w * b4.w;                        \
  }

// symmetric 10-block pair map
#define SYM_PAIR                                                               \
  int bx = blockIdx.x;                                                         \
  int bi = (bx < 4) ? 0 : (bx < 7) ? 1 : (bx < 9) ? 2 : 3;                     \
  int bj = bx - ((bi == 0) ? 0 : (bi == 1) ? 3 : (bi == 2) ? 5 : 6);           \
  int i0 = bi * 64, j0 = bj * 64;

// 3) G = A*A^T per channel (upper tiles + mirror)
__global__ __launch_bounds__(256) void k_gram(const float* __restrict__ x,
                                              float* __restrict__ bufA, int base) {
  __shared__ float As[16][68], Bs[16][68];
  GEMM_VARS; SYM_PAIR;
  const float* A = x + (size_t)(base + blockIdx.z) * NN;
  float acc[4][4] = {};
  float4 pa = *(const float4*)(A + (size_t)(i0 + srow) * N + sq * 4);
  float4 pb = *(const float4*)(A + (size_t)(j0 + srow) * N + sq * 4);
  for (int kt = 0; kt < 16; ++kt) {
    __syncthreads();
    STORE_T(As, pa); STORE_T(Bs, pb);
    __syncthreads();
    if (kt < 15) {
      pa = *(const float4*)(A + (size_t)(i0 + srow) * N + (kt + 1) * 16 + sq * 4);
      pb = *(const float4*)(A + (size_t)(j0 + srow) * N + (kt + 1) * 16 + sq * 4);
    }
    GEMM_INNER16;
  }
  float* Cc = bufA + (size_t)blockIdx.z * NN;
#pragma unroll
  for (int i = 0; i < 4; ++i)
    *(float4*)(Cc + (size_t)(i0 + ty4 + i) * N + j0 + tx4) =
        make_float4(acc[i][0], acc[i][1], acc[i][2], acc[i][3]);
  if (bi != bj) {
#pragma unroll
    for (int cI = 0; cI < 4; ++cI)
      *(float4*)(Cc + (size_t)(j0 + tx4 + cI) * N + i0 + ty4) =
          make_float4(acc[0][cI], acc[1][cI], acc[2][cI], acc[3][cI]);
  }
}

// ---------------------------------------------------------------------------
// 4) Householder tridiag: packed fp32 P in LDS, fp64 arithmetic (R2 numerics)
//    u broadcast via readlane; fp64 w broadcast via same-address LDS read.
// ---------------------------------------------------------------------------
__global__ __launch_bounds__(256) void k_tridiag(const float* __restrict__ Gall,
                                                 float* __restrict__ small, int base) {
  extern __shared__ double dls[];
  double* redd = dls;               // 8 doubles
  double* wd = dls + 8;             // 256 doubles
  float* P = (float*)(dls + 264);   // 32896 floats packed lower
  float* uf = P + 32896;            // 256 floats
  int tid = threadIdx.x, lane = tid & 63;
  int c = base + blockIdx.x;
  const int* ip = (const int*)small;
  if (ip[OFF_MODE + c] != 2) return;
  const float* G = Gall + (size_t)blockIdx.x * NN;
  double* aq = (double*)(small + OFF_AQ) + (size_t)c * 256;
  double* bq = (double*)(small + OFF_BQ) + (size_t)c * 256;
  const int triI = (tid * (tid + 1)) >> 1;

  for (int i = 0; i < N; ++i)
    if (tid <= i) P[((i * (i + 1)) >> 1) + tid] = G[i * N + tid];
  __syncthreads();

  for (int j = 0; j + 2 < N; ++j) {
    if (tid >= j + 1) uf[tid] = P[triI + j];
    __syncthreads();
    double ud = (tid >= j + 1) ? (double)uf[tid] : 0.0;
    double part = (tid >= j + 2) ? ud * ud : 0.0;
    double sigma = block_sum256d(part, redd, tid);
    double x0 = (double)uf[j + 1];
    if (sigma <= 1e-40) { // column already tridiagonal
      if (tid == 0) bq[j] = x0;
      __syncthreads();
      continue;
    }
    double nu = sqrt(x0 * x0 + sigma);
    double bsub = (x0 >= 0.0) ? -nu : nu;
    double beta = 1.0 / (nu * (nu + fabs(x0)));
    if (tid == j + 1) uf[tid] = (float)(x0 - bsub);
    __syncthreads();
    if (tid == j + 1) ud = (double)uf[tid];
    // matvec: pi = sum_l Psym(tid,l)*uf[l], l in [j+1,255]; u via readlane
    double pi0 = 0.0, pi1 = 0.0, pi2 = 0.0, pi3 = 0.0;
    for (int c0 = (j + 1) & ~63; c0 < N; c0 += 64) {
      float ureg = uf[c0 + lane];
      int lbeg = (c0 > j + 1) ? c0 : (j + 1);
      int lend = c0 + 64;
      int lm = lbeg;
      for (; lm + 3 < lend; lm += 4) {
        int s0 = (lm * (lm + 1)) >> 1;
        int s1 = s0 + lm + 1, s2 = s1 + lm + 2, s3 = s2 + lm + 3;
        float uv0 = rdlane(ureg, lm - c0), uv1 = rdlane(ureg, lm + 1 - c0);
        float uv2 = rdlane(ureg, lm + 2 - c0), uv3 = rdlane(ureg, lm + 3 - c0);
        float v0 = P[(lm <= tid) ? (triI + lm) : (s0 + tid)];
        float v1 = P[(lm + 1 <= tid) ? (triI + lm + 1) : (s1 + tid)];
        float v2 = P[(lm + 2 <= tid) ? (triI + lm + 2) : (s2 + tid)];
        float v3 = P[(lm + 3 <= tid) ? (triI + lm + 3) : (s3 + tid)];
        pi0 += (double)v0 * (double)uv0;
        pi1 += (double)v1 * (double)uv1;
        pi2 += (double)v2 * (double)uv2;
        pi3 += (double)v3 * (double)uv3;
      }
      for (; lm < lend; ++lm) {
        int s0 = (lm * (lm + 1)) >> 1;
        float uv0 = rdlane(ureg, lm - c0);
        float v0 = P[(lm <= tid) ? (triI + lm) : (s0 + tid)];
        pi0 += (double)v0 * (double)uv0;
      }
    }
    double pi = (pi0 + pi1 + pi2 + pi3) * beta;
    double kpart = ud * pi; // ud=0 for tid<=j
    double K = block_sum256d(kpart, redd, tid) * beta * 0.5;
    wd[tid] = pi - K * ud;
    __syncthreads();
    // rank-2 update: fp64 arithmetic, fp32 storage (R2 numerics)
    double ui_d = ud, wi_d = wd[tid];
    int wmax = tid | 63; // wave-uniform
    for (int c0 = (j + 1) & ~63; c0 <= wmax; c0 += 64) {
      float ureg = uf[c0 + lane];
      int lbeg = (c0 > j + 1) ? c0 : (j + 1);
      int lend = c0 + 64;
      int lm = lbeg;
      for (; lm + 1 < lend; lm += 2) {
        double uv0 = (double)rdlane(ureg, lm - c0), wv0 = wd[lm];
        double uv1 = (double)rdlane(ureg, lm + 1 - c0), wv1 = wd[lm + 1];
        if (lm <= tid)
          P[triI + lm] = (float)((double)P[triI + lm] - ui_d * wv0 - wi_d * uv0);
        if (lm + 1 <= tid)
          P[triI + lm + 1] =
              (float)((double)P[triI + lm + 1] - ui_d * wv1 - wi_d * uv1);
      }
      if (lm < lend) {
        double uv0 = (double)rdlane(ureg, lm - c0), wv0 = wd[lm];
        if (lm <= tid)
          P[triI + lm] = (float)((double)P[triI + lm] - ui_d * wv0 - wi_d * uv0);
      }
    }
    if (tid == 0) bq[j] = bsub;
    __syncthreads();
  }
  aq[tid] = (double)P[triI + tid];
  if (tid == 0) bq[N - 2] = (double)P[(((N - 1) * N) >> 1) + N - 2];
}

// ---------------------------------------------------------------------------
// 5) fp64 Sturm bisection -> t, alpha, polar-express coefficient schedule
// ---------------------------------------------------------------------------
__device__ __forceinline__ int sturm_count_d(const double* a, const double* b,
                                             double t) {
  double d = a[0] - t;
  int cnt = (d < 0.0);
  for (int i = 1; i < N; ++i) {
    double den = d;
    if (fabs(den) < 1e-20) den = (den < 0.0) ? -1e-20 : 1e-20;
    double bb = b[i - 1];
    d = (a[i] - t) - bb * bb / den;
    cnt += (d < 0.0);
  }
  return cnt; // #{eig < t}
}

__global__ void k_bisect(float* __restrict__ small, int base, int cc) {
  int idx = blockIdx.x * 64 + threadIdx.x;
  if (idx >= cc) return;
  int c = base + idx;
  int* ip = (int*)small;
  if (ip[OFF_MODE + c] != 2) { ip[OFF_MC + c] = 0; return; }
  int k = ip[OFF_K + c];
  const double* a = (const double*)(small + OFF_AQ) + (size_t)c * 256;
  const double* b = (const double*)(small + OFF_BQ) + (size_t)c * 256;
  double lo = 1e300, hi = -1e300;
  for (int i = 0; i < N; ++i) {
    double r = (i > 0 ? fabs(b[i - 1]) : 0.0) + (i < N - 1 ? fabs(b[i]) : 0.0);
    lo = fmin(lo, a[i] - r);
    hi = fmax(hi, a[i] + r);
  }
  double lamk = 0.0, lamk1 = 0.0;
  for (int which = 0; which < 2; ++which) {
    int j = (which == 0) ? (N - k + 1) : (N - k); // ascending index of mu_j
    double l0 = lo, h0 = hi;
    for (int it = 0; it < 60; ++it) {
      double mid = 0.5 * (l0 + h0);
      if (sturm_count_d(a, b, mid) >= j) h0 = mid; else l0 = mid;
    }
    double v = 0.5 * (l0 + h0);
    if (which == 0) lamk = v; else lamk1 = v;
  }
  double t = 0.5 * (lamk + lamk1);
  double gap = fmax(lamk - lamk1, 0.0);
  double alpha = 1.002 * fmax(hi - t, t - lo) + 1e-30;
  double g0 = fmax(gap / (2.0 * alpha), 2e-6);
  // polar-express schedule: equioscillation cubic per iteration (R2 numerics)
  float* cf = small + OFF_COEF + (size_t)c * (2 * NS_MAX);
  double l = fmin(g0, 0.99);
  int m = 0;
  while (m < NS_MAX - 2 && l < 0.9999) {
    double aa = sqrt(27.0 / (4.0 * (1.0 + l + l * l)));
    double bb = (4.0 / 27.0) * aa * aa * aa;
    cf[2 * m] = (float)aa;
    cf[2 * m + 1] = (float)bb;
    double pl = aa * l - bb * l * l * l;
    double p1 = aa - bb;
    l = fmin(pl, p1);
    m++;
  }
  for (int e = 0; e < 2; ++e) { cf[2 * m] = 1.5f; cf[2 * m + 1] = 0.5f; m++; }
  ip[OFF_MC + c] = m;
  ((double*)(small + OFF_T))[c] = t;
  ((double*)(small + OFF_ALPHA))[c] = alpha;
}

// 6) X0 = (G - t*I)/alpha (in place on bufA, fp64 scale)
__global__ void k_x0(const float* __restrict__ small, float* __restrict__ bufA,
                     int base) {
  int ci = blockIdx.y, c = base + ci;
  const int* ip = (const int*)small;
  if (ip[OFF_MODE + c] != 2) return;
  double t = ((const double*)(small + OFF_T))[c];
  double inva = 1.0 / ((const double*)(small + OFF_ALPHA))[c];
  float* X = bufA + (size_t)ci * NN;
  int r = blockIdx.x, tid = threadIdx.x;
  double g = (double)X[r * N + tid];
  if (tid == r) g -= t;
  X[r * N + tid] = (float)(g * inva);
}

// 7a) S = X*X (X symmetric; upper tiles + mirror)
__global__ __launch_bounds__(256) void k_ns1(const float* __restrict__ src,
                                             float* __restrict__ Sb,
                                             const float* __restrict__ small,
                                             int base, int it) {
  const int* ip = (const int*)small;
  int c = base + blockIdx.z;
  if (ip[OFF_MODE + c] != 2 || it >= ip[OFF_MC + c]) return;
  __shared__ float As[16][68], Bs[16][68];
  GEMM_VARS; SYM_PAIR;
  const float* X = src + (size_t)blockIdx.z * NN;
  float acc[4][4] = {};
  float4 pa = *(const float4*)(X + (size_t)(i0 + srow) * N + sq * 4);
  float4 pb = *(const float4*)(X + (size_t)(j0 + srow) * N + sq * 4);
  for (int kt = 0; kt < 16; ++kt) {
    __syncthreads();
    STORE_T(As, pa); STORE_T(Bs, pb);
    __syncthreads();
    if (kt < 15) {
      pa = *(const float4*)(X + (size_t)(i0 + srow) * N + (kt + 1) * 16 + sq * 4);
      pb = *(const float4*)(X + (size_t)(j0 + srow) * N + (kt + 1) * 16 + sq * 4);
    }
    GEMM_INNER16;
  }
  float* Cc = Sb + (size_t)blockIdx.z * NN;
#pragma unroll
  for (int i = 0; i < 4; ++i)
    *(float4*)(Cc + (size_t)(i0 + ty4 + i) * N + j0 + tx4) =
        make_float4(acc[i][0], acc[i][1], acc[i][2], acc[i][3]);
  if (bi != bj) {
#pragma unroll
    for (int cI = 0; cI < 4; ++cI)
      *(float4*)(Cc + (size_t)(j0 + tx4 + cI) * N + i0 + ty4) =
          make_float4(acc[0][cI], acc[1][cI], acc[2][cI], acc[3][cI]);
  }
}

// 7b) Y = a*X - b*X*S (X,S symmetric -> Y symmetric; upper tiles + mirror)
__global__ __launch_bounds__(256) void k_ns2(const float* __restrict__ src,
                                             const float* __restrict__ Sb,
                                             float* __restrict__ dst,
                                             const float* __restrict__ small,
                                             int base, int it) {
  const int* ip = (const int*)small;
  int c = base + blockIdx.z;
  if (ip[OFF_MODE + c] != 2 || it >= ip[OFF_MC + c]) return;
  float ca = small[OFF_COEF + (size_t)c * (2 * NS_MAX) + 2 * it];
  float cb = small[OFF_COEF + (size_t)c * (2 * NS_MAX) + 2 * it + 1];
  __shared__ float As[16][68], Bs[16][68];
  GEMM_VARS; SYM_PAIR;
  const float* X = src + (size_t)blockIdx.z * NN;
  const float* S = Sb + (size_t)blockIdx.z * NN;
  float acc[4][4] = {};
  float4 pa = *(const float4*)(X + (size_t)(i0 + srow) * N + sq * 4);
  float4 pb = *(const float4*)(S + (size_t)(j0 + srow) * N + sq * 4);
  for (int kt = 0; kt < 16; ++kt) {
    __syncthreads();
    STORE_T(As, pa); STORE_T(Bs, pb);
    __syncthreads();
    if (kt < 15) {
      pa = *(const float4*)(X + (size_t)(i0 + srow) * N + (kt + 1) * 16 + sq * 4);
      pb = *(const float4*)(S + (size_t)(j0 + srow) * N + (kt + 1) * 16 + sq * 4);
    }
    GEMM_INNER16;
  }
  float xr[4][4];
#pragma unroll
  for (int i = 0; i < 4; ++i) {
    float4 t = *(const float4*)(X + (size_t)(i0 + ty4 + i) * N + j0 + tx4);
    xr[i][0] = t.x; xr[i][1] = t.y; xr[i][2] = t.z; xr[i][3] = t.w;
  }
  float* Y = dst + (size_t)blockIdx.z * NN;
#pragma unroll
  for (int i = 0; i < 4; ++i)
    *(float4*)(Y + (size_t)(i0 + ty4 + i) * N + j0 + tx4) =
        make_float4(ca * xr[i][0] - cb * acc[i][0], ca * xr[i][1] - cb * acc[i][1],
                    ca * xr[i][2] - cb * acc[i][2], ca * xr[i][3] - cb * acc[i][3]);
  if (bi != bj) {
#pragma unroll
    for (int cI = 0; cI < 4; ++cI)
      *(float4*)(Y + (size_t)(j0 + tx4 + cI) * N + i0 + ty4) =
          make_float4(ca * xr[0][cI] - cb * acc[0][cI], ca * xr[1][cI] - cb * acc[1][cI],
                      ca * xr[2][cI] - cb * acc[2][cI], ca * xr[3][cI] - cb * acc[3][cI]);
  }
}

// 8) A_k = 0.5*(sign(X)*A + A) (modes: 0 -> zeros, 1 -> copy A)
__global__ __launch_bounds__(256) void k_proj(const float* __restrict__ bufA,
                                              const float* __restrict__ bufB,
                                              const float* __restrict__ x,
                                              float* __restrict__ bufC,
                                              const float* __restrict__ small,
                                              int base) {
  const int* ip = (const int*)small;
  int ci = blockIdx.z, c = base + ci;
  int mode = ip[OFF_MODE + c];
  GEMM_VARS;
  int i0 = blockIdx.x * 64, j0 = blockIdx.y * 64;
  float* Cc = bufC + (size_t)ci * NN;
  const float* xc = x + (size_t)c * NN;
  if (mode == 0) {
#pragma unroll
    for (int i = 0; i < 4; ++i)
      *(float4*)(Cc + (size_t)(i0 + ty4 + i) * N + j0 + tx4) =
          make_float4(0.f, 0.f, 0.f, 0.f);
    return;
  }
  if (mode == 1) {
#pragma unroll
    for (int i = 0; i < 4; ++i)
      *(float4*)(Cc + (size_t)(i0 + ty4 + i) * N + j0 + tx4) =
          *(const float4*)(xc + (size_t)(i0 + ty4 + i) * N + j0 + tx4);
    return;
  }
  int mc = ip[OFF_MC + c];
  const float* Xh = ((mc & 1) ? bufB : bufA) + (size_t)ci * NN;
  __shared__ float As[16][68], Bs[16][68];
  float acc[4][4] = {};
  float4 pa = *(const float4*)(Xh + (size_t)(i0 + srow) * N + sq * 4);
  float4 pb = *(const float4*)(xc + (size_t)skk * N + j0 + sj4);
  for (int kt = 0; kt < 16; ++kt) {
    __syncthreads();
    STORE_T(As, pa);
    *(float4*)&Bs[skk][sj4] = pb;
    __syncthreads();
    if (kt < 15) {
      pa = *(const float4*)(Xh + (size_t)(i0 + srow) * N + (kt + 1) * 16 + sq * 4);
      pb = *(const float4*)(xc + (size_t)((kt + 1) * 16 + skk) * N + j0 + sj4);
    }
    GEMM_INNER16;
  }
#pragma unroll
  for (int i = 0; i < 4; ++i) {
    const float4 xr = *(const float4*)(xc + (size_t)(i0 + ty4 + i) * N + j0 + tx4);
    *(float4*)(Cc + (size_t)(i0 + ty4 + i) * N + j0 + tx4) =
        make_float4(0.5f * (acc[i][0] + xr.x), 0.5f * (acc[i][1] + xr.y),
                    0.5f * (acc[i][2] + xr.z), 0.5f * (acc[i][3] + xr.w));
  }
}

// 9) accumulate sum & max over channels
__global__ void k_accum(const float* __restrict__ bufC, float* __restrict__ sum_hw,
                        float* __restrict__ max_hw, int cc, int first) {
  int p = blockIdx.x * 256 + threadIdx.x;
  float s = first ? 0.f : sum_hw[p];
  float m = first ? -1e30f : max_hw[p];
  for (int ci = 0; ci < cc; ++ci) {
    float v = bufC[(size_t)ci * NN + p];
    s += v;
    m = fmaxf(m, v);
  }
  sum_hw[p] = s;
  max_hw[p] = m;
}

// 10) 7x7 conv (pad 3) on [avg, max] -> clamp EPS -> sigmoid
__global__ void k_conv(const float* __restrict__ sum_hw, const float* __restrict__ max_hw,
                       const float* __restrict__ cw, float* __restrict__ out) {
  int p = blockIdx.x * 256 + threadIdx.x;
  int h = p >> 8, w = p & 255;
  float acc = 0.f;
  for (int dy = 0; dy < 7; ++dy) {
    int hy = h + dy - 3;
    if (hy < 0 || hy > 255) continue;
    for (int dx = 0; dx < 7; ++dx) {
      int wx = w + dx - 3;
      if (wx < 0 || wx > 255) continue;
      int q = hy * 256 + wx;
      acc += cw[dy * 7 + dx] * (sum_hw[q] * (1.f / 256.f)) +
             cw[49 + dy * 7 + dx] * max_hw[q];
    }
  }
  acc = fmaxf(acc, EPSF);
  out[p] = 1.f / (1.f + expf(-acc));
}

// ---------------------------------------------------------------------------
extern "C" void kernel_launch(void* const* d_in, const int* in_sizes, int n_in,
                              void* d_out, int out_size, void* d_ws, size_t ws_size,
                              hipStream_t stream) {
  const float* x = (const float*)d_in[0];
  const float* w1 = (const float*)d_in[1];
  const float* w2 = (const float*)d_in[2];
  const float* cw = (const float*)d_in[3];
  const int* kv = (const int*)d_in[4];
  float* out = (float*)d_out;
  float* small = (float*)d_ws;

  size_t small_bytes = (size_t)SMALL_FLOATS * 4;
  size_t avail = ws_size > small_bytes ? ws_size - small_bytes : 0;
  long chunk = (long)(avail / (3ull * NN * 4)); // 3 fp32 matrices per channel
  if (chunk > NCH) chunk = NCH;
  if (chunk < 1) chunk = 1;
  float* bufA = small + SMALL_FLOATS;
  float* bufB = bufA + (size_t)chunk * NN;
  float* bufC = bufB + (size_t)chunk * NN;

  const int tridiag_lds = 264 * 8 + 32896 * 4 + 256 * 4; // 134720 B
  hipFuncSetAttribute((const void*)k_tridiag,
                      hipFuncAttributeMaxDynamicSharedMemorySize, tridiag_lds);

  k_chan_stats<<<NCH, 256, 0, stream>>>(x, small);
  k_attention<<<1, 256, 0, stream>>>(w1, w2, kv, small);

  for (int base = 0; base < NCH; base += (int)chunk) {
    int cc = (NCH - base < (int)chunk) ? (NCH - base) : (int)chunk;
    dim3 gsym(10, 1, cc);
    dim3 g44(4, 4, cc);
    k_gram<<<gsym, 256, 0, stream>>>(x, bufA, base);
    k_tridiag<<<cc, 256, tridiag_lds, stream>>>(bufA, small, base);
    k_bisect<<<(cc + 63) / 64, 64, 0, stream>>>(small, base, cc);
    k_x0<<<dim3(N, cc), 256, 0, stream>>>(small, bufA, base);
    for (int it = 0; it < NS_MAX; ++it) {
      const float* src = (it & 1) ? bufB : bufA;
      float* dst = (it & 1) ? bufA : bufB;
      k_ns1<<<gsym, 256, 0, stream>>>(src, bufC, small, base, it);
      k_ns2<<<gsym, 256, 0, stream>>>(src, bufC, dst, small, base, it);
    }
    k_proj<<<g44, 256, 0, stream>>>(bufA, bufB, x, bufC, small, base);
    k_accum<<<256, 256, 0, stream>>>(bufC, small + OFF_SUM, small + OFF_MAXHW, cc,
                                     base == 0 ? 1 : 0);
  }
  k_conv<<<256, 256, 0, stream>>>(small + OFF_SUM, small + OFF_MAXHW, cw, out);
}

// Round 6
// 9204.762 us; speedup vs baseline: 1.3899x; 1.0875x over previous
//
#include <hip/hip_runtime.h>

// ============================================================================
// AFAR: channel-attention -> per-channel truncated-SVD recon -> spatial attn.
// A_k = P*A, P = step(G - t), G = A*A^T. t from mixed-precision Householder
// tridiag (fp32 LDS storage, fp64 arithmetic, 1024 threads: 4 l-chunk groups
// x 256 rows) + fp64 Sturm bisect. Projector via polar-express sign schedule;
// symmetric GEMMs: 128x128 tiles, 8x8 micro-tile, 3/4 blocks + mirror.
// FIX vs R5: ureg loads hoisted to wave-uniform condition (rdlane reads
// registers of exec-masked lanes -> producer load must run on ALL lanes).
// ============================================================================

#define NCH 256
#define N 256
#define NN 65536
#define NS_MAX 22

// small-region float offsets inside d_ws (double regions 8B-aligned)
#define OFF_K 0          // int[256]
#define OFF_MODE 256     // int[256]: 0 -> A_k=0, 1 -> A_k=A, 2 -> project
#define OFF_MC 512       // int[256]
#define OFF_COEF 768     // float[256][2*NS_MAX]
#define OFF_SUM 12032    // float[65536]
#define OFF_MAXHW 77568  // float[65536]
#define OFF_MEAND 143104 // double[256]
#define OFF_MAXD 143616  // double[256]
#define OFF_T 144128     // double[256]
#define OFF_ALPHA 144640 // double[256]
#define OFF_AQ 145152    // double[256][256]
#define OFF_BQ 276224    // double[256][256]
#define SMALL_FLOATS 407296

static const float EPSF = 2.220446049250313e-16f;

__device__ __forceinline__ float rdlane(float v, int l) {
  return __uint_as_float(__builtin_amdgcn_readlane(__float_as_uint(v), l));
}

__device__ __forceinline__ double block_sum1024d(double v, double* red, int tid) {
  for (int off = 32; off; off >>= 1) v += __shfl_down(v, off, 64);
  __syncthreads(); // protect red from previous use
  if ((tid & 63) == 0) red[tid >> 6] = v;
  __syncthreads();
  double s = 0.0;
#pragma unroll
  for (int i = 0; i < 16; ++i) s += red[i];
  return s;
}

// ---------------------------------------------------------------------------
// 1) per-channel mean & max over H*W (fp64 sum)
// ---------------------------------------------------------------------------
__global__ __launch_bounds__(256) void k_chan_stats(const float* __restrict__ x,
                                                    float* __restrict__ small) {
  int c = blockIdx.x, tid = threadIdx.x;
  const float4* xc = (const float4*)(x + (size_t)c * NN);
  double s = 0.0;
  float m = -1e30f;
  for (int i = tid; i < NN / 4; i += 256) {
    float4 v = xc[i];
    s += (double)v.x + (double)v.y + (double)v.z + (double)v.w;
    m = fmaxf(m, fmaxf(fmaxf(v.x, v.y), fmaxf(v.z, v.w)));
  }
  __shared__ double rs[4];
  __shared__ float rm[4];
  for (int off = 32; off; off >>= 1) {
    s += __shfl_down(s, off, 64);
    m = fmaxf(m, __shfl_down(m, off, 64));
  }
  if ((tid & 63) == 0) { rs[tid >> 6] = s; rm[tid >> 6] = m; }
  __syncthreads();
  if (tid == 0) {
    ((double*)(small + OFF_MEAND))[c] = (rs[0] + rs[1] + rs[2] + rs[3]) / (double)NN;
    ((double*)(small + OFF_MAXD))[c] =
        (double)fmaxf(fmaxf(rm[0], rm[1]), fmaxf(rm[2], rm[3]));
  }
}

// ---------------------------------------------------------------------------
// 2) shared-MLP channel attention (fp64) -> gates yc -> k_c, mode_c
// ---------------------------------------------------------------------------
__global__ __launch_bounds__(256) void k_attention(const float* __restrict__ w1,
                                                   const float* __restrict__ w2,
                                                   const int* __restrict__ kvp,
                                                   float* __restrict__ small) {
  int tid = threadIdx.x;
  __shared__ double ha[16], hm[16], redd[8], ymn[256], ymx[256];
  double va = ((const double*)(small + OFF_MEAND))[tid];
  double vm = ((const double*)(small + OFF_MAXD))[tid];
  for (int r = 0; r < 16; ++r) {
    double wv = (double)w1[r * 256 + tid];
    double pa = wv * va, pm = wv * vm;
    for (int off = 32; off; off >>= 1) {
      pa += __shfl_down(pa, off, 64);
      pm += __shfl_down(pm, off, 64);
    }
    if ((tid & 63) == 0) { redd[tid >> 6] = pa; redd[4 + (tid >> 6)] = pm; }
    __syncthreads();
    if (tid == 0) {
      ha[r] = fmax(redd[0] + redd[1] + redd[2] + redd[3], 0.0);
      hm[r] = fmax(redd[4] + redd[5] + redd[6] + redd[7], 0.0);
    }
    __syncthreads();
  }
  double ya = 0.0, ym = 0.0;
  for (int r = 0; r < 16; ++r) {
    double wv = (double)w2[tid * 16 + r];
    ya += ha[r] * wv;
    ym += hm[r] * wv;
  }
  double y = 1.0 / (1.0 + exp(-(ya + ym)));
  ymn[tid] = y; ymx[tid] = y;
  __syncthreads();
  for (int off = 128; off; off >>= 1) {
    if (tid < off) {
      ymn[tid] = fmin(ymn[tid], ymn[tid + off]);
      ymx[tid] = fmax(ymx[tid], ymx[tid + off]);
    }
    __syncthreads();
  }
  double yc = (y - ymn[0]) / (ymx[0] - ymn[0] + 1e-20);
  int kv = kvp[0];
  int k = (int)floor(256.0 * (double)kv * yc);
  int mode = (k <= 0) ? 0 : ((k >= 256) ? 1 : 2);
  int* ip = (int*)small;
  ip[OFF_K + tid] = k;
  ip[OFF_MODE + tid] = mode;
}

// ---------------------------------------------------------------------------
// GEMM core: 128x128 tile, 256 threads, 8x8 micro-tile (2x2 quadrants of 4)
// ---------------------------------------------------------------------------
#define GEMM128_VARS                                                           \
  int tid = threadIdx.x;                                                       \
  int tx4 = (tid & 15) * 4, ty4 = (tid >> 4) * 4;                              \
  int lm = tid >> 1, lq = (tid & 1) * 2;                                       \
  int lk = tid >> 4, lc = (tid & 15) * 2;                                      \
  (void)lk; (void)lc;

#define STORE_T128(Ls, v0, v1)                                                 \
  Ls[lq * 4 + 0][lm] = v0.x; Ls[lq * 4 + 1][lm] = v0.y;                        \
  Ls[lq * 4 + 2][lm] = v0.z; Ls[lq * 4 + 3][lm] = v0.w;                        \
  Ls[lq * 4 + 4][lm] = v1.x; Ls[lq * 4 + 5][lm] = v1.y;                        \
  Ls[lq * 4 + 6][lm] = v1.z; Ls[lq * 4 + 7][lm] = v1.w;

#define GEMM128_INNER(AsM, BsM)                                                \
  _Pragma("unroll") for (int kk = 0; kk < 16; ++kk) {                          \
    float4 a0 = *(const float4*)&AsM[kk][ty4];                                 \
    float4 a1 = *(const float4*)&AsM[kk][64 + ty4];                            \
    float4 b0 = *(const float4*)&BsM[kk][tx4];                                 \
    float4 b1 = *(const float4*)&BsM[kk][64 + tx4];                            \
    float av[8] = {a0.x, a0.y, a0.z, a0.w, a1.x, a1.y, a1.z, a1.w};            \
    float bv[8] = {b0.x, b0.y, b0.z, b0.w, b1.x, b1.y, b1.z, b1.w};            \
    _Pragma("unroll") for (int rr = 0; rr < 8; ++rr)                           \
      _Pragma("unroll") for (int cc2 = 0; cc2 < 8; ++cc2)                      \
        acc[rr][cc2] += av[rr] * bv[cc2];                                      \
  }

#define WRITE_TILE_NORM(Cc)                                                    \
  _Pragma("unroll") for (int rh = 0; rh < 2; ++rh)                             \
  _Pragma("unroll") for (int rr = 0; rr < 4; ++rr) {                           \
    int rI = rh * 4 + rr;                                                      \
    float* rowp = (Cc) + (size_t)(i0 + rh * 64 + ty4 + rr) * N + j0;           \
    *(float4*)(rowp + tx4) =                                                   \
        make_float4(acc[rI][0], acc[rI][1], acc[rI][2], acc[rI][3]);           \
    *(float4*)(rowp + 64 + tx4) =                                              \
        make_float4(acc[rI][4], acc[rI][5], acc[rI][6], acc[rI][7]);           \
  }

#define WRITE_TILE_MIRROR(Cc)                                                  \
  _Pragma("unroll") for (int ch = 0; ch < 2; ++ch)                             \
  _Pragma("unroll") for (int cc2 = 0; cc2 < 4; ++cc2) {                        \
    int cI = ch * 4 + cc2;                                                     \
    float* rowp = (Cc) + (size_t)(j0 + ch * 64 + tx4 + cc2) * N + i0;          \
    *(float4*)(rowp + ty4) =                                                   \
        make_float4(acc[0][cI], acc[1][cI], acc[2][cI], acc[3][cI]);           \
    *(float4*)(rowp + 64 + ty4) =                                              \
        make_float4(acc[4][cI], acc[5][cI], acc[6][cI], acc[7][cI]);           \
  }

// sym block map: bx 0,1,2 -> (0,0),(1,0),(1,1)
#define SYM_MAP                                                                \
  int bx = blockIdx.x;                                                         \
  int i0 = (bx >= 1) ? 128 : 0, j0 = (bx == 2) ? 128 : 0;

// 3) G = A*A^T per channel (lower tiles + mirror)
__global__ __launch_bounds__(256) void k_gram(const float* __restrict__ x,
                                              float* __restrict__ bufA, int base) {
  __shared__ float As[16][132], Bs[16][132];
  GEMM128_VARS; SYM_MAP;
  const float* A = x + (size_t)(base + blockIdx.z) * NN;
  float acc[8][8] = {};
  const float* Ap = A + (size_t)(i0 + lm) * N + lq * 4;
  const float* Bp = A + (size_t)(j0 + lm) * N + lq * 4;
  float4 va0 = *(const float4*)Ap, va1 = *(const float4*)(Ap + 4);
  float4 vb0 = *(const float4*)Bp, vb1 = *(const float4*)(Bp + 4);
  for (int kt = 0; kt < 16; ++kt) {
    __syncthreads();
    STORE_T128(As, va0, va1); STORE_T128(Bs, vb0, vb1);
    __syncthreads();
    if (kt < 15) {
      va0 = *(const float4*)(Ap + (kt + 1) * 16);
      va1 = *(const float4*)(Ap + (kt + 1) * 16 + 4);
      vb0 = *(const float4*)(Bp + (kt + 1) * 16);
      vb1 = *(const float4*)(Bp + (kt + 1) * 16 + 4);
    }
    GEMM128_INNER(As, Bs);
  }
  float* Cc = bufA + (size_t)blockIdx.z * NN;
  WRITE_TILE_NORM(Cc);
  if (bx == 1) { WRITE_TILE_MIRROR(Cc); }
}

// ---------------------------------------------------------------------------
// 4) Householder tridiag: 1024 threads = 4 l-chunk groups x 256 rows.
//    fp32 P in LDS, fp64 arithmetic (R2/R4 numerics mod fp64 reassociation).
//    NOTE: ureg (rdlane source) is loaded under WAVE-UNIFORM conditions only.
// ---------------------------------------------------------------------------
__global__ __launch_bounds__(1024) void k_tridiag(const float* __restrict__ Gall,
                                                  float* __restrict__ small, int base) {
  extern __shared__ double dls[];
  double* redd = dls;              // 16
  double* wd = dls + 16;           // 256
  double* pip = dls + 272;         // 1024
  float* P = (float*)(dls + 1296); // 32896 packed lower triangle
  float* uf = P + 32896;           // 256
  int tid = threadIdx.x, lane = tid & 63;
  int r = tid & 255, g = tid >> 8;
  int c = base + blockIdx.x;
  const int* ip = (const int*)small;
  if (ip[OFF_MODE + c] != 2) return;
  const float* G = Gall + (size_t)blockIdx.x * NN;
  double* aq = (double*)(small + OFF_AQ) + (size_t)c * 256;
  double* bq = (double*)(small + OFF_BQ) + (size_t)c * 256;
  const int triR = (r * (r + 1)) >> 1;

  for (int i = g; i < N; i += 4)
    if (r <= i) P[((i * (i + 1)) >> 1) + r] = G[i * N + r];
  __syncthreads();

  for (int j = 0; j + 2 < N; ++j) {
    if (g == 0 && r >= j + 1) uf[r] = P[triR + j];
    __syncthreads();
    float ur0 = uf[r];
    double part = (g == 0 && r >= j + 2) ? (double)ur0 * (double)ur0 : 0.0;
    double x0 = (double)uf[j + 1];
    double sigma = block_sum1024d(part, redd, tid);
    if (sigma <= 1e-40) { // column already tridiagonal
      if (tid == 0) bq[j] = x0;
      __syncthreads();
      continue;
    }
    double nu = sqrt(x0 * x0 + sigma);
    double bsub = (x0 >= 0.0) ? -nu : nu;
    double beta = 1.0 / (nu * (nu + fabs(x0)));
    if (tid == j + 1) uf[tid] = (float)(x0 - bsub); // g==0, r==j+1
    __syncthreads();
    int cbase = (j + 1) & ~63;
    int c0 = cbase + 64 * g; // wave-uniform (g, cbase uniform)
    // load rdlane source on ALL lanes (uniform condition only!)
    float ureg = 0.f;
    if (c0 < N) ureg = uf[c0 + lane];
    // matvec partial over chunk g: sum_l Psym(r,l)*u[l]
    double myp = 0.0;
    if (c0 < N && r >= j + 1) {
      int lbeg = (c0 > j + 1) ? c0 : (j + 1);
      int lend = c0 + 64;
      double pi0 = 0.0, pi1 = 0.0, pi2 = 0.0, pi3 = 0.0;
      int lmv = lbeg;
      for (; lmv + 3 < lend; lmv += 4) {
        int s0 = (lmv * (lmv + 1)) >> 1;
        int s1 = s0 + lmv + 1, s2 = s1 + lmv + 2, s3 = s2 + lmv + 3;
        float uv0 = rdlane(ureg, lmv - c0), uv1 = rdlane(ureg, lmv + 1 - c0);
        float uv2 = rdlane(ureg, lmv + 2 - c0), uv3 = rdlane(ureg, lmv + 3 - c0);
        float v0 = P[(lmv <= r) ? (triR + lmv) : (s0 + r)];
        float v1 = P[(lmv + 1 <= r) ? (triR + lmv + 1) : (s1 + r)];
        float v2 = P[(lmv + 2 <= r) ? (triR + lmv + 2) : (s2 + r)];
        float v3 = P[(lmv + 3 <= r) ? (triR + lmv + 3) : (s3 + r)];
        pi0 += (double)v0 * (double)uv0;
        pi1 += (double)v1 * (double)uv1;
        pi2 += (double)v2 * (double)uv2;
        pi3 += (double)v3 * (double)uv3;
      }
      for (; lmv < lend; ++lmv) {
        int s0 = (lmv * (lmv + 1)) >> 1;
        float uv0 = rdlane(ureg, lmv - c0);
        float v0 = P[(lmv <= r) ? (triR + lmv) : (s0 + r)];
        pi0 += (double)v0 * (double)uv0;
      }
      myp = (pi0 + pi1) + (pi2 + pi3);
    }
    pip[tid] = myp;
    __syncthreads();
    double ur = (r >= j + 1) ? (double)uf[r] : 0.0; // v-value at j+1
    double pi = 0.0;
    if (g == 0 && r >= j + 1)
      pi = (pip[r] + pip[256 + r] + pip[512 + r] + pip[768 + r]) * beta;
    double kpart = (g == 0) ? ur * pi : 0.0;
    double K = block_sum1024d(kpart, redd, tid) * beta * 0.5;
    if (g == 0) wd[r] = pi - K * ur;
    __syncthreads();
    // rank-2 update on chunk g: P[r][l] -= u_r*w_l + w_r*u_l, l in [j+1, r]
    if (c0 < N && r >= j + 1) {
      double wr = wd[r];
      int lbeg = (c0 > j + 1) ? c0 : (j + 1);
      int lend = c0 + 64;
      int lcap = (r | 63) + 1; // wave-uniform cap
      if (lend > lcap) lend = lcap;
      int lmv = lbeg;
      for (; lmv + 1 < lend; lmv += 2) {
        double uv0 = (double)rdlane(ureg, lmv - c0), wv0 = wd[lmv];
        double uv1 = (double)rdlane(ureg, lmv + 1 - c0), wv1 = wd[lmv + 1];
        if (lmv <= r)
          P[triR + lmv] = (float)((double)P[triR + lmv] - ur * wv0 - wr * uv0);
        if (lmv + 1 <= r)
          P[triR + lmv + 1] =
              (float)((double)P[triR + lmv + 1] - ur * wv1 - wr * uv1);
      }
      if (lmv < lend) {
        double uv0 = (double)rdlane(ureg, lmv - c0), wv0 = wd[lmv];
        if (lmv <= r)
          P[triR + lmv] = (float)((double)P[triR + lmv] - ur * wv0 - wr * uv0);
      }
    }
    if (tid == 0) bq[j] = bsub;
    __syncthreads();
  }
  if (g == 0) aq[r] = (double)P[triR + r];
  if (tid == 0) bq[N - 2] = (double)P[(((N - 1) * N) >> 1) + N - 2];
}

// ---------------------------------------------------------------------------
// 5) fp64 Sturm bisection -> t, alpha, polar-express coefficient schedule
// ---------------------------------------------------------------------------
__device__ __forceinline__ int sturm_count_d(const double* a, const double* b,
                                             double t) {
  double d = a[0] - t;
  int cnt = (d < 0.0);
  for (int i = 1; i < N; ++i) {
    double den = d;
    if (fabs(den) < 1e-20) den = (den < 0.0) ? -1e-20 : 1e-20;
    double bb = b[i - 1];
    d = (a[i] - t) - bb * bb / den;
    cnt += (d < 0.0);
  }
  return cnt; // #{eig < t}
}

__global__ void k_bisect(float* __restrict__ small, int base, int cc) {
  int idx = blockIdx.x * 64 + threadIdx.x;
  if (idx >= cc) return;
  int c = base + idx;
  int* ip = (int*)small;
  if (ip[OFF_MODE + c] != 2) { ip[OFF_MC + c] = 0; return; }
  int k = ip[OFF_K + c];
  const double* a = (const double*)(small + OFF_AQ) + (size_t)c * 256;
  const double* b = (const double*)(small + OFF_BQ) + (size_t)c * 256;
  double lo = 1e300, hi = -1e300;
  for (int i = 0; i < N; ++i) {
    double r = (i > 0 ? fabs(b[i - 1]) : 0.0) + (i < N - 1 ? fabs(b[i]) : 0.0);
    lo = fmin(lo, a[i] - r);
    hi = fmax(hi, a[i] + r);
  }
  double lamk = 0.0, lamk1 = 0.0;
  for (int which = 0; which < 2; ++which) {
    int j = (which == 0) ? (N - k + 1) : (N - k); // ascending index of mu_j
    double l0 = lo, h0 = hi;
    for (int it = 0; it < 60; ++it) {
      double mid = 0.5 * (l0 + h0);
      if (sturm_count_d(a, b, mid) >= j) h0 = mid; else l0 = mid;
    }
    double v = 0.5 * (l0 + h0);
    if (which == 0) lamk = v; else lamk1 = v;
  }
  double t = 0.5 * (lamk + lamk1);
  double gap = fmax(lamk - lamk1, 0.0);
  double alpha = 1.002 * fmax(hi - t, t - lo) + 1e-30;
  double g0 = fmax(gap / (2.0 * alpha), 2e-6);
  // polar-express schedule: equioscillation cubic per iteration (R2 numerics)
  float* cf = small + OFF_COEF + (size_t)c * (2 * NS_MAX);
  double l = fmin(g0, 0.99);
  int m = 0;
  while (m < NS_MAX - 2 && l < 0.9999) {
    double aa = sqrt(27.0 / (4.0 * (1.0 + l + l * l)));
    double bb = (4.0 / 27.0) * aa * aa * aa;
    cf[2 * m] = (float)aa;
    cf[2 * m + 1] = (float)bb;
    double pl = aa * l - bb * l * l * l;
    double p1 = aa - bb;
    l = fmin(pl, p1);
    m++;
  }
  for (int e = 0; e < 2; ++e) { cf[2 * m] = 1.5f; cf[2 * m + 1] = 0.5f; m++; }
  ip[OFF_MC + c] = m;
  ((double*)(small + OFF_T))[c] = t;
  ((double*)(small + OFF_ALPHA))[c] = alpha;
}

// 6) X0 = (G - t*I)/alpha (in place on bufA, fp64 scale)
__global__ void k_x0(const float* __restrict__ small, float* __restrict__ bufA,
                     int base) {
  int ci = blockIdx.y, c = base + ci;
  const int* ip = (const int*)small;
  if (ip[OFF_MODE + c] != 2) return;
  double t = ((const double*)(small + OFF_T))[c];
  double inva = 1.0 / ((const double*)(small + OFF_ALPHA))[c];
  float* X = bufA + (size_t)ci * NN;
  int r = blockIdx.x, tid = threadIdx.x;
  double gg = (double)X[r * N + tid];
  if (tid == r) gg -= t;
  X[r * N + tid] = (float)(gg * inva);
}

// 7a) S = X*X (X symmetric; lower tiles + mirror)
__global__ __launch_bounds__(256) void k_ns1(const float* __restrict__ src,
                                             float* __restrict__ Sb,
                                             const float* __restrict__ small,
                                             int base, int it) {
  const int* ip = (const int*)small;
  int c = base + blockIdx.z;
  if (ip[OFF_MODE + c] != 2 || it >= ip[OFF_MC + c]) return;
  __shared__ float As[16][132], Bs[16][132];
  GEMM128_VARS; SYM_MAP;
  const float* X = src + (size_t)blockIdx.z * NN;
  float acc[8][8] = {};
  const float* Ap = X + (size_t)(i0 + lm) * N + lq * 4;
  const float* Bp = X + (size_t)(j0 + lm) * N + lq * 4;
  float4 va0 = *(const float4*)Ap, va1 = *(const float4*)(Ap + 4);
  float4 vb0 = *(const float4*)Bp, vb1 = *(const float4*)(Bp + 4);
  for (int kt = 0; kt < 16; ++kt) {
    __syncthreads();
    STORE_T128(As, va0, va1); STORE_T128(Bs, vb0, vb1);
    __syncthreads();
    if (kt < 15) {
      va0 = *(const float4*)(Ap + (kt + 1) * 16);
      va1 = *(const float4*)(Ap + (kt + 1) * 16 + 4);
      vb0 = *(const float4*)(Bp + (kt + 1) * 16);
      vb1 = *(const float4*)(Bp + (kt + 1) * 16 + 4);
    }
    GEMM128_INNER(As, Bs);
  }
  float* Cc = Sb + (size_t)blockIdx.z * NN;
  WRITE_TILE_NORM(Cc);
  if (bx == 1) { WRITE_TILE_MIRROR(Cc); }
}

// 7b) Y = a*X - b*X*S (commuting symmetric -> Y symmetric; tiles + mirror)
__global__ __launch_bounds__(256) void k_ns2(const float* __restrict__ src,
                                             const float* __restrict__ Sb,
                                             float* __restrict__ dst,
                                             const float* __restrict__ small,
                                             int base, int it) {
  const int* ip = (const int*)small;
  int c = base + blockIdx.z;
  if (ip[OFF_MODE + c] != 2 || it >= ip[OFF_MC + c]) return;
  float ca = small[OFF_COEF + (size_t)c * (2 * NS_MAX) + 2 * it];
  float cb = small[OFF_COEF + (size_t)c * (2 * NS_MAX) + 2 * it + 1];
  __shared__ float As[16][132], Bs[16][132];
  GEMM128_VARS; SYM_MAP;
  const float* X = src + (size_t)blockIdx.z * NN;
  const float* S = Sb + (size_t)blockIdx.z * NN;
  float acc[8][8] = {};
  const float* Ap = X + (size_t)(i0 + lm) * N + lq * 4;
  const float* Bp = S + (size_t)(j0 + lm) * N + lq * 4;
  float4 va0 = *(const float4*)Ap, va1 = *(const float4*)(Ap + 4);
  float4 vb0 = *(const float4*)Bp, vb1 = *(const float4*)(Bp + 4);
  for (int kt = 0; kt < 16; ++kt) {
    __syncthreads();
    STORE_T128(As, va0, va1); STORE_T128(Bs, vb0, vb1);
    __syncthreads();
    if (kt < 15) {
      va0 = *(const float4*)(Ap + (kt + 1) * 16);
      va1 = *(const float4*)(Ap + (kt + 1) * 16 + 4);
      vb0 = *(const float4*)(Bp + (kt + 1) * 16);
      vb1 = *(const float4*)(Bp + (kt + 1) * 16 + 4);
    }
    GEMM128_INNER(As, Bs);
  }
  // acc <- ca*X - cb*acc (transform in place, then write norm + mirror)
#pragma unroll
  for (int rh = 0; rh < 2; ++rh)
#pragma unroll
    for (int rr = 0; rr < 4; ++rr) {
      int rI = rh * 4 + rr;
      const float* rowp = X + (size_t)(i0 + rh * 64 + ty4 + rr) * N + j0;
      float4 x0 = *(const float4*)(rowp + tx4);
      float4 x1 = *(const float4*)(rowp + 64 + tx4);
      acc[rI][0] = ca * x0.x - cb * acc[rI][0];
      acc[rI][1] = ca * x0.y - cb * acc[rI][1];
      acc[rI][2] = ca * x0.z - cb * acc[rI][2];
      acc[rI][3] = ca * x0.w - cb * acc[rI][3];
      acc[rI][4] = ca * x1.x - cb * acc[rI][4];
      acc[rI][5] = ca * x1.y - cb * acc[rI][5];
      acc[rI][6] = ca * x1.z - cb * acc[rI][6];
      acc[rI][7] = ca * x1.w - cb * acc[rI][7];
    }
  float* Y = dst + (size_t)blockIdx.z * NN;
  WRITE_TILE_NORM(Y);
  if (bx == 1) { WRITE_TILE_MIRROR(Y); }
}

// 8) A_k = 0.5*(sign(X)*A + A) (modes: 0 -> zeros, 1 -> copy A)
__global__ __launch_bounds__(256) void k_proj(const float* __restrict__ bufA,
                                              const float* __restrict__ bufB,
                                              const float* __restrict__ x,
                                              float* __restrict__ bufC,
                                              const float* __restrict__ small,
                                              int base) {
  const int* ip = (const int*)small;
  int ci = blockIdx.z, c = base + ci;
  int mode = ip[OFF_MODE + c];
  GEMM128_VARS;
  int i0 = blockIdx.x * 128, j0 = blockIdx.y * 128;
  float* Cc = bufC + (size_t)ci * NN;
  const float* xc = x + (size_t)c * NN;
  if (mode != 2) {
#pragma unroll
    for (int rh = 0; rh < 2; ++rh)
#pragma unroll
      for (int rr = 0; rr < 4; ++rr) {
        size_t ro = (size_t)(i0 + rh * 64 + ty4 + rr) * N + j0;
        if (mode == 0) {
          *(float4*)(Cc + ro + tx4) = make_float4(0.f, 0.f, 0.f, 0.f);
          *(float4*)(Cc + ro + 64 + tx4) = make_float4(0.f, 0.f, 0.f, 0.f);
        } else {
          *(float4*)(Cc + ro + tx4) = *(const float4*)(xc + ro + tx4);
          *(float4*)(Cc + ro + 64 + tx4) = *(const float4*)(xc + ro + 64 + tx4);
        }
      }
    return;
  }
  int mc = ip[OFF_MC + c];
  const float* Xh = ((mc & 1) ? bufB : bufA) + (size_t)ci * NN;
  __shared__ float As[16][132], Bs[16][132];
  float acc[8][8] = {};
  const float* Ap = Xh + (size_t)(i0 + lm) * N + lq * 4;
  const float* Bp = xc + (size_t)lk * N + j0 + lc * 4;
  float4 va0 = *(const float4*)Ap, va1 = *(const float4*)(Ap + 4);
  float4 vb0 = *(const float4*)Bp, vb1 = *(const float4*)(Bp + 4);
  for (int kt = 0; kt < 16; ++kt) {
    __syncthreads();
    STORE_T128(As, va0, va1);
    *(float4*)&Bs[lk][lc * 4] = vb0;
    *(float4*)&Bs[lk][(lc + 1) * 4] = vb1;
    __syncthreads();
    if (kt < 15) {
      va0 = *(const float4*)(Ap + (kt + 1) * 16);
      va1 = *(const float4*)(Ap + (kt + 1) * 16 + 4);
      const float* Bp2 = xc + (size_t)((kt + 1) * 16 + lk) * N + j0 + lc * 4;
      vb0 = *(const float4*)Bp2;
      vb1 = *(const float4*)(Bp2 + 4);
    }
    GEMM128_INNER(As, Bs);
  }
#pragma unroll
  for (int rh = 0; rh < 2; ++rh)
#pragma unroll
    for (int rr = 0; rr < 4; ++rr) {
      int rI = rh * 4 + rr;
      const float* rowp = xc + (size_t)(i0 + rh * 64 + ty4 + rr) * N + j0;
      float4 x0 = *(const float4*)(rowp + tx4);
      float4 x1 = *(const float4*)(rowp + 64 + tx4);
      acc[rI][0] = 0.5f * (acc[rI][0] + x0.x);
      acc[rI][1] = 0.5f * (acc[rI][1] + x0.y);
      acc[rI][2] = 0.5f * (acc[rI][2] + x0.z);
      acc[rI][3] = 0.5f * (acc[rI][3] + x0.w);
      acc[rI][4] = 0.5f * (acc[rI][4] + x1.x);
      acc[rI][5] = 0.5f * (acc[rI][5] + x1.y);
      acc[rI][6] = 0.5f * (acc[rI][6] + x1.z);
      acc[rI][7] = 0.5f * (acc[rI][7] + x1.w);
    }
  WRITE_TILE_NORM(Cc);
}

// 9) accumulate sum & max over channels
__global__ void k_accum(const float* __restrict__ bufC, float* __restrict__ sum_hw,
                        float* __restrict__ max_hw, int cc, int first) {
  int p = blockIdx.x * 256 + threadIdx.x;
  float s = first ? 0.f : sum_hw[p];
  float m = first ? -1e30f : max_hw[p];
  for (int ci = 0; ci < cc; ++ci) {
    float v = bufC[(size_t)ci * NN + p];
    s += v;
    m = fmaxf(m, v);
  }
  sum_hw[p] = s;
  max_hw[p] = m;
}

// 10) 7x7 conv (pad 3) on [avg, max] -> clamp EPS -> sigmoid
__global__ void k_conv(const float* __restrict__ sum_hw, const float* __restrict__ max_hw,
                       const float* __restrict__ cw, float* __restrict__ out) {
  int p = blockIdx.x * 256 + threadIdx.x;
  int h = p >> 8, w = p & 255;
  float acc = 0.f;
  for (int dy = 0; dy < 7; ++dy) {
    int hy = h + dy - 3;
    if (hy < 0 || hy > 255) continue;
    for (int dx = 0; dx < 7; ++dx) {
      int wx = w + dx - 3;
      if (wx < 0 || wx > 255) continue;
      int q = hy * 256 + wx;
      acc += cw[dy * 7 + dx] * (sum_hw[q] * (1.f / 256.f)) +
             cw[49 + dy * 7 + dx] * max_hw[q];
    }
  }
  acc = fmaxf(acc, EPSF);
  out[p] = 1.f / (1.f + expf(-acc));
}

// ---------------------------------------------------------------------------
extern "C" void kernel_launch(void* const* d_in, const int* in_sizes, int n_in,
                              void* d_out, int out_size, void* d_ws, size_t ws_size,
                              hipStream_t stream) {
  const float* x = (const float*)d_in[0];
  const float* w1 = (const float*)d_in[1];
  const float* w2 = (const float*)d_in[2];
  const float* cw = (const float*)d_in[3];
  const int* kv = (const int*)d_in[4];
  float* out = (float*)d_out;
  float* small = (float*)d_ws;

  size_t small_bytes = (size_t)SMALL_FLOATS * 4;
  size_t avail = ws_size > small_bytes ? ws_size - small_bytes : 0;
  long chunk = (long)(avail / (3ull * NN * 4)); // 3 fp32 matrices per channel
  if (chunk > NCH) chunk = NCH;
  if (chunk < 1) chunk = 1;
  float* bufA = small + SMALL_FLOATS;
  float* bufB = bufA + (size_t)chunk * NN;
  float* bufC = bufB + (size_t)chunk * NN;

  const int tridiag_lds = 1296 * 8 + 32896 * 4 + 256 * 4; // 142976 B
  hipFuncSetAttribute((const void*)k_tridiag,
                      hipFuncAttributeMaxDynamicSharedMemorySize, tridiag_lds);

  k_chan_stats<<<NCH, 256, 0, stream>>>(x, small);
  k_attention<<<1, 256, 0, stream>>>(w1, w2, kv, small);

  for (int base = 0; base < NCH; base += (int)chunk) {
    int cc = (NCH - base < (int)chunk) ? (NCH - base) : (int)chunk;
    dim3 gsym(3, 1, cc);
    dim3 gproj(2, 2, cc);
    k_gram<<<gsym, 256, 0, stream>>>(x, bufA, base);
    k_tridiag<<<cc, 1024, tridiag_lds, stream>>>(bufA, small, base);
    k_bisect<<<(cc + 63) / 64, 64, 0, stream>>>(small, base, cc);
    k_x0<<<dim3(N, cc), 256, 0, stream>>>(small, bufA, base);
    for (int it = 0; it < NS_MAX; ++it) {
      const float* src = (it & 1) ? bufB : bufA;
      float* dst = (it & 1) ? bufA : bufB;
      k_ns1<<<gsym, 256, 0, stream>>>(src, bufC, small, base, it);
      k_ns2<<<gsym, 256, 0, stream>>>(src, bufC, dst, small, base, it);
    }
    k_proj<<<gproj, 256, 0, stream>>>(bufA, bufB, x, bufC, small, base);
    k_accum<<<256, 256, 0, stream>>>(bufC, small + OFF_SUM, small + OFF_MAXHW, cc,
                                     base == 0 ? 1 : 0);
  }
  k_conv<<<256, 256, 0, stream>>>(small + OFF_SUM, small + OFF_MAXHW, cw, out);
}